// Round 9
// baseline (584.094 us; speedup 1.0000x reference)
//
#include <hip/hip_runtime.h>

// Problem constants
#define T_ 64
#define B_ 512
#define D_ 768
#define H_ 12
#define HD_ 64
#define M1 (T_*B_)        // 32768 rows for both GEMMs
#define N_QKV (3*D_)      // 2304

typedef __attribute__((ext_vector_type(8))) short short8;
typedef __attribute__((ext_vector_type(4))) float f32x4;

__device__ __forceinline__ unsigned short f2b(float f) {
  unsigned int u = __float_as_uint(f);
  u = (u + 0x7FFFu + ((u >> 16) & 1u)) >> 16;   // RNE
  return (unsigned short)u;
}
__device__ __forceinline__ float b2f(unsigned short s) {
  return __uint_as_float(((unsigned int)s) << 16);
}

// async 16B global -> LDS (wave-uniform LDS base + lane*16 scatter semantics)
__device__ __forceinline__ void load_lds16(const unsigned short* g, unsigned short* l) {
  __builtin_amdgcn_global_load_lds(
      (const __attribute__((address_space(1))) unsigned int*)g,
      (__attribute__((address_space(3))) unsigned int*)l, 16, 0, 0);
}

// ---- fused fp32 -> bf16 casts (node / wqkv / wout in one launch) ----
#define N4_NODE 6291456
#define N4_WQKV 442368
#define N4_WOUT 147456
__global__ __launch_bounds__(256) void k_cast_all(
    const float* __restrict__ node, const float* __restrict__ wqkv,
    const float* __restrict__ wout, unsigned short* __restrict__ x_bf,
    unsigned short* __restrict__ wqkv_bf, unsigned short* __restrict__ wout_bf) {
  int i = blockIdx.x * 256 + threadIdx.x;
  const float* src; unsigned short* dst; int off;
  if (i < N4_NODE)                 { src = node; dst = x_bf;    off = i; }
  else if (i < N4_NODE + N4_WQKV)  { src = wqkv; dst = wqkv_bf; off = i - N4_NODE; }
  else                             { src = wout; dst = wout_bf; off = i - N4_NODE - N4_WQKV; }
  float4 v = ((const float4*)src)[off];
  ushort4 o;
  o.x = f2b(v.x); o.y = f2b(v.y); o.z = f2b(v.z); o.w = f2b(v.w);
  ((ushort4*)dst)[off] = o;
}

// ============ Shared GEMM staging/fragment pattern (128x128 tile, BK=64) ============
// LDS packed [row][64 shorts], 16B chunk (row,c) at slot c^(row&7).
// Staging conflict-free; fragment reads 2-way aliased (free per m136).
#define GEMM_STAGE(Aptr, Bptr) \
    __syncthreads(); \
    _Pragma("unroll") \
    for (int it = 0; it < 4; it++) { \
      int s = wave*256 + it*64 + lane; \
      int r = s >> 3, cp = s & 7, c = cp ^ (r & 7); \
      load_lds16(&Aptr[(size_t)(m0+r)*768 + k0 + c*8], &As[s*8]); \
      load_lds16(&Bptr[(size_t)(n0+r)*768 + k0 + c*8], &Bs[s*8]); \
    } \
    __syncthreads();

#define GEMM_FRAGS \
      short8 a[4], b[4]; \
      _Pragma("unroll") \
      for (int i = 0; i < 4; i++) { \
        int row = wm + i*16 + ln; \
        int cp = (j*4 + quad) ^ (row & 7); \
        a[i] = *(const short8*)&As[row*64 + cp*8]; \
      } \
      _Pragma("unroll") \
      for (int i = 0; i < 4; i++) { \
        int row = wn + i*16 + ln; \
        int cp = (j*4 + quad) ^ (row & 7); \
        b[i] = *(const short8*)&Bs[row*64 + cp*8]; \
      }

// ---- QKV projection. XCD-swizzled. q/k use SWAPPED mfma (acc spans e -> coalesced
// ushort4 into [T,H,B,HD]); v unswapped (acc spans b -> coalesced ushort4 into [T,H,HD,B]).
__global__ __launch_bounds__(256) void k_gemm_qkv(
    const unsigned short* __restrict__ A,    // [32768,768] bf16
    const unsigned short* __restrict__ Bw,   // [2304,768]  bf16
    const float* __restrict__ bias,          // [2304]
    unsigned short* __restrict__ qo,
    unsigned short* __restrict__ ko,
    unsigned short* __restrict__ vTo)
{
  __shared__ __align__(16) unsigned short As[128*64];
  __shared__ __align__(16) unsigned short Bs[128*64];
  const int tid = threadIdx.x;
  const int bb = blockIdx.x;                 // 4608 blocks
  const int xcd = bb & 7, idx = bb >> 3;     // idx in [0,576)
  const int m0 = (xcd*32 + idx/18) * 128;    // same-XCD blocks share m-stripe
  const int n0 = (idx%18) * 128;             // n sweeps fastest -> A-tile L2 reuse
  const bool isqk = (n0 < 1536);
  const int lane = tid & 63, wave = tid >> 6;
  const int ln = lane & 15, quad = lane >> 4;
  const int wm = (wave & 1) * 64, wn = (wave >> 1) * 64;
  f32x4 acc[4][4] = {};
  for (int k0 = 0; k0 < 768; k0 += 64) {
    GEMM_STAGE(A, Bw)
#pragma unroll
    for (int j = 0; j < 2; j++) {
      GEMM_FRAGS
      if (isqk) {
#pragma unroll
        for (int mi = 0; mi < 4; mi++)
#pragma unroll
          for (int ni = 0; ni < 4; ni++)
            acc[mi][ni] = __builtin_amdgcn_mfma_f32_16x16x32_bf16(b[ni], a[mi], acc[mi][ni], 0, 0, 0);
      } else {
#pragma unroll
        for (int mi = 0; mi < 4; mi++)
#pragma unroll
          for (int ni = 0; ni < 4; ni++)
            acc[mi][ni] = __builtin_amdgcn_mfma_f32_16x16x32_bf16(a[mi], b[ni], acc[mi][ni], 0, 0, 0);
      }
    }
  }
  const int t = m0 >> 9;
  if (isqk) {
    // D^T: acc[mi][ni] rows = e (quad*4+r), cols = m (ln). 4 consecutive e = contiguous hd.
    unsigned short* dst = (n0 < 768) ? qo : ko;
    const int ebase = (n0 < 768) ? n0 : (n0 - 768);
#pragma unroll
    for (int ni = 0; ni < 4; ni++) {
      int ecol = ebase + wn + ni*16 + quad*4;       // within part, 4-aligned
      int h = ecol >> 6, hd0 = ecol & 63;
      float4 bi = *(const float4*)&bias[n0 + wn + ni*16 + quad*4];
#pragma unroll
      for (int mi = 0; mi < 4; mi++) {
        int brow = (m0 & 511) + wm + mi*16 + ln;
        ushort4 pk;
        pk.x = f2b(acc[mi][ni][0] + bi.x);
        pk.y = f2b(acc[mi][ni][1] + bi.y);
        pk.z = f2b(acc[mi][ni][2] + bi.z);
        pk.w = f2b(acc[mi][ni][3] + bi.w);
        *(ushort4*)&dst[((size_t)(t*H_ + h)*B_ + brow)*HD_ + hd0] = pk;
      }
    }
  } else {
    // D: acc[mi][ni] rows = m (quad*4+r), cols = e (ln). 4 consecutive b contiguous in [hd][b].
#pragma unroll
    for (int ni = 0; ni < 4; ni++) {
      int ecol = (n0 - 1536) + wn + ni*16 + ln;
      int h = ecol >> 6, hd = ecol & 63;
      float bi = bias[n0 + wn + ni*16 + ln];
#pragma unroll
      for (int mi = 0; mi < 4; mi++) {
        int brow = (m0 & 511) + wm + mi*16 + quad*4;
        ushort4 pk;
        pk.x = f2b(acc[mi][ni][0] + bi);
        pk.y = f2b(acc[mi][ni][1] + bi);
        pk.z = f2b(acc[mi][ni][2] + bi);
        pk.w = f2b(acc[mi][ni][3] + bi);
        *(ushort4*)&vTo[((size_t)(t*H_ + h)*HD_ + hd)*B_ + brow] = pk;
      }
    }
  }
}

// ---- Out projection -> bf16, SWAPPED mfma (acc spans n -> coalesced ushort4). ----
__global__ __launch_bounds__(256) void k_gemm_out(
    const unsigned short* __restrict__ A,    // [32768,768] bf16 (ctx)
    const unsigned short* __restrict__ Bw,   // [768,768] bf16
    const float* __restrict__ bias,          // [768]
    unsigned short* __restrict__ outb)       // [32768,768] bf16
{
  __shared__ __align__(16) unsigned short As[128*64];
  __shared__ __align__(16) unsigned short Bs[128*64];
  const int tid = threadIdx.x;
  const int bb = blockIdx.x;                 // 1536 blocks
  const int xcd = bb & 7, idx = bb >> 3;     // idx in [0,192)
  const int m0 = (xcd*32 + idx/6) * 128;
  const int n0 = (idx%6) * 128;
  const int lane = tid & 63, wave = tid >> 6;
  const int ln = lane & 15, quad = lane >> 4;
  const int wm = (wave & 1) * 64, wn = (wave >> 1) * 64;
  f32x4 acc[4][4] = {};
  for (int k0 = 0; k0 < 768; k0 += 64) {
    GEMM_STAGE(A, Bw)
#pragma unroll
    for (int j = 0; j < 2; j++) {
      GEMM_FRAGS
#pragma unroll
      for (int mi = 0; mi < 4; mi++)
#pragma unroll
        for (int ni = 0; ni < 4; ni++)
          acc[mi][ni] = __builtin_amdgcn_mfma_f32_16x16x32_bf16(b[ni], a[mi], acc[mi][ni], 0, 0, 0);
    }
  }
  // D^T: rows = n (quad*4+r), cols = m (ln). 4 consecutive n contiguous in row-major out.
#pragma unroll
  for (int ni = 0; ni < 4; ni++) {
    int ncol = n0 + wn + ni*16 + quad*4;
    float4 bi = *(const float4*)&bias[ncol];
#pragma unroll
    for (int mi = 0; mi < 4; mi++) {
      int mrow = m0 + wm + mi*16 + ln;
      ushort4 pk;
      pk.x = f2b(acc[mi][ni][0] + bi.x);
      pk.y = f2b(acc[mi][ni][1] + bi.y);
      pk.z = f2b(acc[mi][ni][2] + bi.z);
      pk.w = f2b(acc[mi][ni][3] + bi.w);
      *(ushort4*)&outb[(size_t)mrow*768 + ncol] = pk;
    }
  }
}

// ---- MFMA attention: 256-thread blocks, wave owns 32 q-rows (2 subtiles).
// 32 MFMAs per wave between barrier pairs. Block = (t,h, 128 q-rows). XCD-swizzled.
__global__ __launch_bounds__(256) void k_attn(
    const unsigned short* __restrict__ q,    // [T,H,B,HD]
    const unsigned short* __restrict__ k,    // [T,H,B,HD]
    const unsigned short* __restrict__ vT,   // [T,H,HD,B]
    unsigned short* __restrict__ ctx)        // [T,B,D]
{
  __shared__ __align__(16) unsigned short Ks[64*64];   // packed, chunk c^(r&7)
  __shared__ __align__(16) unsigned short VT[64*64];   // packed, chunk c^(r&7)
  __shared__ __align__(16) unsigned short Ps[4*32*72]; // per-wave P (32 rows), col^16quad swizzle
  const int tid = threadIdx.x;
  const int lane = tid & 63, wave = tid >> 6;          // wave 0..3
  const int ln = lane & 15, quad = lane >> 4;
  const int bb = blockIdx.x;                 // 3072 blocks
  const int xcd = bb & 7, idx = bb >> 3;     // idx in [0,384)
  const int th = xcd*96 + (idx >> 2);        // t*12+h ; th's 4 blocks share XCD
  const int q0 = (idx & 3) * 128;
  const int t = th / H_, h = th - t*H_;
  const size_t base  = (size_t)th * (B_*HD_);   // q,k base
  const size_t baseT = (size_t)th * (HD_*B_);   // vT base

  // Q fragments: this wave's 32 q-rows (2 subtiles of 16), A-layout, in registers
  short8 qf[2][2];
#pragma unroll
  for (int s = 0; s < 2; s++) {
    const unsigned short* qp = &q[base + (size_t)(q0 + wave*32 + s*16 + ln)*HD_ + quad*8];
    qf[s][0] = *(const short8*)qp;
    qf[s][1] = *(const short8*)(qp + 32);
  }
  f32x4 acc[2][4] = {};          // [q-subtile][dim-subtile], rows quad*4+r, col ln
  float dpart[2][4] = {};
  unsigned short* Pw = &Ps[wave*32*72];

  for (int kt = 0; kt < B_; kt += 64) {
    __syncthreads();
    // async-stage K chunk [64 keys][64 dims] and V^T chunk [64 dims][64 keys]
#pragma unroll
    for (int it = 0; it < 2; it++) {
      int s = it*256 + tid;
      int r = s >> 3, cp = s & 7, c = cp ^ (r & 7);
      load_lds16(&k[base + (size_t)(kt + r)*HD_ + c*8], &Ks[s*8]);
      load_lds16(&vT[baseT + (size_t)r*B_ + kt + c*8], &VT[s*8]);
    }
    __syncthreads();
    // QK^T: 4 key-subtiles x 2 q-subtiles, K-dim 64 = 2 MFMAs each
    f32x4 sf[2][4] = {};
#pragma unroll
    for (int ki = 0; ki < 4; ki++) {
      int row = ki*16 + ln;
      short8 b0 = *(const short8*)&Ks[row*64 + (quad     ^ (row & 7))*8];
      short8 b1 = *(const short8*)&Ks[row*64 + ((4+quad) ^ (row & 7))*8];
#pragma unroll
      for (int s = 0; s < 2; s++) {
        sf[s][ki] = __builtin_amdgcn_mfma_f32_16x16x32_bf16(qf[s][0], b0, sf[s][ki], 0, 0, 0);
        sf[s][ki] = __builtin_amdgcn_mfma_f32_16x16x32_bf16(qf[s][1], b1, sf[s][ki], 0, 0, 0);
      }
    }
    // exp (fp32), denominator, P to wave-local LDS
#pragma unroll
    for (int s = 0; s < 2; s++)
#pragma unroll
      for (int ki = 0; ki < 4; ki++) {
        int colbase = (ki*16 + ln) ^ (quad*16);
#pragma unroll
        for (int r = 0; r < 4; r++) {
          float p = __expf(sf[s][ki][r] * 0.125f);   // 1/sqrt(64)
          dpart[s][r] += p;
          Pw[(s*16 + quad*4 + r)*72 + colbase] = f2b(p);
        }
      }
    // PV: A-frags from Pw (row=s*16+ln, keys hf*32+quad*8+j, unswizzle ^16*((ln>>2)&3))
    short8 pa[2][2];
#pragma unroll
    for (int s = 0; s < 2; s++)
#pragma unroll
      for (int hf = 0; hf < 2; hf++) {
        int cc = (hf*32 + quad*8) ^ (16*((ln >> 2) & 3));
        pa[s][hf] = *(const short8*)&Pw[(s*16 + ln)*72 + cc];
      }
#pragma unroll
    for (int ds = 0; ds < 4; ds++) {
      int row = ds*16 + ln;                  // dim
      short8 vb0 = *(const short8*)&VT[row*64 + (quad     ^ (row & 7))*8];
      short8 vb1 = *(const short8*)&VT[row*64 + ((4+quad) ^ (row & 7))*8];
#pragma unroll
      for (int s = 0; s < 2; s++) {
        acc[s][ds] = __builtin_amdgcn_mfma_f32_16x16x32_bf16(pa[s][0], vb0, acc[s][ds], 0, 0, 0);
        acc[s][ds] = __builtin_amdgcn_mfma_f32_16x16x32_bf16(pa[s][1], vb1, acc[s][ds], 0, 0, 0);
      }
    }
  }
  // denominator: sum over 16-lane column group; write ctx [T,B,D] bf16
#pragma unroll
  for (int s = 0; s < 2; s++) {
#pragma unroll
    for (int r = 0; r < 4; r++) {
      float d = dpart[s][r];
      d += __shfl_xor(d, 1); d += __shfl_xor(d, 2);
      d += __shfl_xor(d, 4); d += __shfl_xor(d, 8);
      dpart[s][r] = 1.f / d;
    }
    int qrow = q0 + wave*32 + s*16 + quad*4;
#pragma unroll
    for (int r = 0; r < 4; r++) {
      size_t o = ((size_t)t*B_ + (qrow + r))*D_ + h*HD_ + ln;
#pragma unroll
      for (int ds = 0; ds < 4; ds++)
        ctx[o + ds*16] = f2b(acc[s][ds][r] * dpart[s][r]);
    }
  }
}

// ---- Norms + partial mean-normalized vectors (bf16 input). 512 blocks. ----
__global__ __launch_bounds__(256) void k_norms1(const unsigned short* __restrict__ outb,
                                                float* __restrict__ norms,
                                                float* __restrict__ pmvec)
{
  __shared__ float wsum[4*768];
  int blk = blockIdx.x;            // t*8 + c
  int t = blk >> 3, c = blk & 7;
  int wave = threadIdx.x >> 6, lane = threadIdx.x & 63;
  float macc[12];
#pragma unroll
  for (int j = 0; j < 12; j++) macc[j] = 0.f;
  for (int i = 0; i < 16; i++) {
    int b = c*64 + wave*16 + i;
    const unsigned short* row = &outb[((size_t)t*B_ + b)*D_];
    float x[12]; float ss = 0.f;
#pragma unroll
    for (int j = 0; j < 12; j++) { x[j] = b2f(row[lane + 64*j]); ss += x[j]*x[j]; }
#pragma unroll
    for (int off = 32; off; off >>= 1) ss += __shfl_xor(ss, off);
    float nr = fmaxf(sqrtf(ss), 1e-8f);
    if (lane == 0) norms[(size_t)t*B_ + b] = nr;
    float inv = 1.f / nr;
#pragma unroll
    for (int j = 0; j < 12; j++) macc[j] += x[j]*inv;
  }
#pragma unroll
  for (int j = 0; j < 12; j++) wsum[wave*768 + 64*j + lane] = macc[j];
  __syncthreads();
  for (int d = threadIdx.x; d < 768; d += 256) {
    pmvec[(size_t)blk*768 + d] = wsum[d] + wsum[768 + d] + wsum[1536 + d] + wsum[2304 + d];
  }
}

// ---- reduce 8 partials -> mvec[t] ----
__global__ __launch_bounds__(256) void k_norms2(const float* __restrict__ pmvec,
                                                float* __restrict__ mvec)
{
  int t = blockIdx.x;
  for (int d = threadIdx.x; d < 768; d += 256) {
    float s = 0.f;
#pragma unroll
    for (int c = 0; c < 8; c++) s += pmvec[(size_t)(t*8 + c)*768 + d];
    mvec[t*768 + d] = s * (1.0f/512.0f);
  }
}

// ---- adj[t,b] = mvec[t] . out[t,b] / norms[t,b]. One wave per row (bf16 input). ----
__global__ __launch_bounds__(256) void k_adj(const unsigned short* __restrict__ outb,
                                             const float* __restrict__ norms,
                                             const float* __restrict__ mvec,
                                             float* __restrict__ adj)
{
  int idx = blockIdx.x*4 + (threadIdx.x >> 6);   // 0..32767
  int lane = threadIdx.x & 63;
  int t = idx >> 9;
  const unsigned short* row = &outb[(size_t)idx*768];
  const float* m = &mvec[t*768];
  float dot = 0.f;
#pragma unroll
  for (int j = 0; j < 12; j++) dot += b2f(row[lane + 64*j]) * m[lane + 64*j];
#pragma unroll
  for (int off = 32; off; off >>= 1) dot += __shfl_xor(dot, off);
  if (lane == 0) adj[idx] = dot / norms[idx];
}

extern "C" void kernel_launch(void* const* d_in, const int* in_sizes, int n_in,
                              void* d_out, int out_size, void* d_ws, size_t ws_size,
                              hipStream_t stream)
{
  const float* node = (const float*)d_in[0];  // (64,512,768)
  const float* wqkv = (const float*)d_in[1];  // (2304,768)
  const float* bqkv = (const float*)d_in[2];  // (2304,)
  const float* wout = (const float*)d_in[3];  // (768,768)
  const float* bout = (const float*)d_in[4];  // (768,)
  float* adj = (float*)d_out;                 // (64,512,1)

  char* ws = (char*)d_ws;
  const size_t SZ = (size_t)M1*D_*2;          // 50,331,648 B (one bf16 [32768,768] buf)
  // Layout (~245 MiB). out_bf (48 MiB) aliases q (dead after attn).
  // pmvec (1.5 MiB) aliases x_bf (dead after qkv gemm).
  unsigned short* q_bf    = (unsigned short*)(ws);
  unsigned short* k_bf    = (unsigned short*)(ws + SZ);
  unsigned short* vT_bf   = (unsigned short*)(ws + 2*SZ);
  unsigned short* ctx_bf  = (unsigned short*)(ws + 3*SZ);
  unsigned short* x_bf    = (unsigned short*)(ws + 4*SZ);
  unsigned short* wqkv_bf = (unsigned short*)(ws + 5*SZ);
  unsigned short* wout_bf = (unsigned short*)(ws + 5*SZ + 3538944);
  unsigned short* out_bf  = (unsigned short*)(ws);                          // alias q
  float* pmvec            = (float*)(ws + 4*SZ);                            // alias x_bf
  float* norms            = (float*)(ws + 5*SZ + 3538944 + 1179648);
  float* mvec             = (float*)(ws + 5*SZ + 3538944 + 1179648 + 131072);

  // 1) fused casts to bf16
  k_cast_all<<<26880, 256, 0, stream>>>(node, wqkv, wout, x_bf, wqkv_bf, wout_bf);
  // 2) QKV projection (XCD-swizzled, operand-swap coalesced epilogues)
  k_gemm_qkv<<<4608, 256, 0, stream>>>(x_bf, wqkv_bf, bqkv, q_bf, k_bf, vT_bf);
  // 3) attention (32 q-rows/wave, XCD-swizzled)
  k_attn<<<3072, 256, 0, stream>>>(q_bf, k_bf, vT_bf, ctx_bf);
  // 4) out projection (operand-swap coalesced epilogue) -> bf16 out (aliases q space)
  k_gemm_out<<<1536, 256, 0, stream>>>(ctx_bf, wout_bf, bout, out_bf);
  // 5) norms + mean normalized vector per t (512-block partial + reduce)
  k_norms1<<<T_*8, 256, 0, stream>>>(out_bf, norms, pmvec);
  k_norms2<<<T_, 256, 0, stream>>>(pmvec, mvec);
  // 6) adj = mvec . xn
  k_adj<<<M1/4, 256, 0, stream>>>(out_bf, norms, mvec, adj);
}

// Round 10
// 459.292 us; speedup vs baseline: 1.2717x; 1.2717x over previous
//
#include <hip/hip_runtime.h>

// Problem constants
#define T_ 64
#define B_ 512
#define D_ 768
#define H_ 12
#define HD_ 64
#define M1 (T_*B_)        // 32768 rows for both GEMMs
#define N_QKV (3*D_)      // 2304

typedef __attribute__((ext_vector_type(8))) short short8;
typedef __attribute__((ext_vector_type(4))) float f32x4;

__device__ __forceinline__ unsigned short f2b(float f) {
  unsigned int u = __float_as_uint(f);
  u = (u + 0x7FFFu + ((u >> 16) & 1u)) >> 16;   // RNE
  return (unsigned short)u;
}
__device__ __forceinline__ float b2f(unsigned short s) {
  return __uint_as_float(((unsigned int)s) << 16);
}

// async 16B global -> LDS (wave-uniform LDS base + lane*16 scatter semantics)
__device__ __forceinline__ void load_lds16(const unsigned short* g, unsigned short* l) {
  __builtin_amdgcn_global_load_lds(
      (const __attribute__((address_space(1))) unsigned int*)g,
      (__attribute__((address_space(3))) unsigned int*)l, 16, 0, 0);
}

// ---- fused fp32 -> bf16 casts (node / wqkv / wout in one launch) ----
#define N4_NODE 6291456
#define N4_WQKV 442368
#define N4_WOUT 147456
__global__ __launch_bounds__(256) void k_cast_all(
    const float* __restrict__ node, const float* __restrict__ wqkv,
    const float* __restrict__ wout, unsigned short* __restrict__ x_bf,
    unsigned short* __restrict__ wqkv_bf, unsigned short* __restrict__ wout_bf) {
  int i = blockIdx.x * 256 + threadIdx.x;
  const float* src; unsigned short* dst; int off;
  if (i < N4_NODE)                 { src = node; dst = x_bf;    off = i; }
  else if (i < N4_NODE + N4_WQKV)  { src = wqkv; dst = wqkv_bf; off = i - N4_NODE; }
  else                             { src = wout; dst = wout_bf; off = i - N4_NODE - N4_WQKV; }
  float4 v = ((const float4*)src)[off];
  ushort4 o;
  o.x = f2b(v.x); o.y = f2b(v.y); o.z = f2b(v.z); o.w = f2b(v.w);
  ((ushort4*)dst)[off] = o;
}

// ============ GEMM core (128x128 tile, BK=64, global_load_lds + XOR swizzle) ============
// LDS packed [row][64 shorts], 16B chunk (row,c) at slot c^(row&7).
// Staging conflict-free; fragment reads 2-way aliased (free per m136).
#define GEMM_BODY(Aptr, Bptr) \
  unsigned short* As = Sbuf; \
  unsigned short* Bs = Sbuf + 8192; \
  const int lane = tid & 63, wave = tid >> 6; \
  const int ln = lane & 15, quad = lane >> 4; \
  const int wm = (wave & 1) * 64, wn = (wave >> 1) * 64; \
  f32x4 acc[4][4] = {}; \
  for (int k0 = 0; k0 < 768; k0 += 64) { \
    __syncthreads(); \
    _Pragma("unroll") \
    for (int it = 0; it < 4; it++) { \
      int s = wave*256 + it*64 + lane; \
      int r = s >> 3, cp = s & 7, c = cp ^ (r & 7); \
      load_lds16(&Aptr[(size_t)(m0+r)*768 + k0 + c*8], &As[s*8]); \
      load_lds16(&Bptr[(size_t)(n0+r)*768 + k0 + c*8], &Bs[s*8]); \
    } \
    __syncthreads(); \
    _Pragma("unroll") \
    for (int j = 0; j < 2; j++) { \
      short8 a[4], b[4]; \
      _Pragma("unroll") \
      for (int i = 0; i < 4; i++) { \
        int row = wm + i*16 + ln; \
        int cp = (j*4 + quad) ^ (row & 7); \
        a[i] = *(const short8*)&As[row*64 + cp*8]; \
      } \
      _Pragma("unroll") \
      for (int i = 0; i < 4; i++) { \
        int row = wn + i*16 + ln; \
        int cp = (j*4 + quad) ^ (row & 7); \
        b[i] = *(const short8*)&Bs[row*64 + cp*8]; \
      } \
      _Pragma("unroll") \
      for (int mi = 0; mi < 4; mi++) \
        _Pragma("unroll") \
        for (int ni = 0; ni < 4; ni++) \
          acc[mi][ni] = __builtin_amdgcn_mfma_f32_16x16x32_bf16(a[mi], b[ni], acc[mi][ni], 0, 0, 0); \
    } \
  }

// Repack acc (+bias per column) into Sbuf as [row 0..127][col 0..127], stride 136.
#define EPILOG_REPACK(BIASEXPR) \
  __syncthreads(); \
  _Pragma("unroll") \
  for (int ni = 0; ni < 4; ni++) { \
    int col = wn + ni*16 + ln; \
    float bi = (BIASEXPR); \
    _Pragma("unroll") \
    for (int mi = 0; mi < 4; mi++) { \
      int row = wm + mi*16 + quad*4; \
      _Pragma("unroll") \
      for (int r = 0; r < 4; r++) \
        Sbuf[(row + r)*136 + col] = f2b(acc[mi][ni][r] + bi); \
    } \
  } \
  __syncthreads();

// ---- QKV projection. XCD-swizzled. All epilogues repack through LDS -> coalesced 16B stores.
__global__ __launch_bounds__(256) void k_gemm_qkv(
    const unsigned short* __restrict__ A,    // [32768,768] bf16
    const unsigned short* __restrict__ Bw,   // [2304,768]  bf16
    const float* __restrict__ bias,          // [2304]
    unsigned short* __restrict__ qo,
    unsigned short* __restrict__ ko,
    unsigned short* __restrict__ vTo)
{
  __shared__ __align__(16) unsigned short Sbuf[128*136];  // K-loop uses first 32 KB
  const int tid = threadIdx.x;
  const int bb = blockIdx.x;                 // 4608 blocks
  const int xcd = bb & 7, idx = bb >> 3;     // idx in [0,576)
  const int m0 = (xcd*32 + idx/18) * 128;    // same-XCD blocks share m-stripe
  const int n0 = (idx%18) * 128;             // n sweeps fastest -> A-tile L2 reuse
  GEMM_BODY(A, Bw)
  const int t = m0 >> 9;

  if (n0 < 1536) {
    // ---- q/k: repack [b-row][e-col] then stream coalesced into [T,H,B,HD] ----
    EPILOG_REPACK(bias[n0 + col])
    unsigned short* dst = (n0 < 768) ? qo : ko;
    const int colbase = (n0 < 768) ? n0 : (n0 - 768);
#pragma unroll
    for (int kk = 0; kk < 8; kk++) {
      int ci = kk*256 + tid;                 // 2048 chunks of 8 shorts
      int r2 = ci >> 4, c2 = (ci & 15) * 8;  // row 0..127, col start
      int within = colbase + c2;
      int h = within >> 6, hd = within & 63;
      *(uint4*)&dst[((size_t)(t*H_ + h)*B_ + (m0 & 511) + r2)*HD_ + hd] =
          *(const uint4*)&Sbuf[r2*136 + c2];
    }
  } else {
    // ---- v: repack transposed [e-col][b-row] then stream coalesced into [T,H,HD,B] ----
    __syncthreads();
#pragma unroll
    for (int mi = 0; mi < 4; mi++)
#pragma unroll
      for (int ni = 0; ni < 4; ni++) {
        int col = wn + ni*16 + ln;
        int row = wm + mi*16 + quad*4;
        float bi = bias[n0 + col];
        ushort4 pk;
        pk.x = f2b(acc[mi][ni][0] + bi);
        pk.y = f2b(acc[mi][ni][1] + bi);
        pk.z = f2b(acc[mi][ni][2] + bi);
        pk.w = f2b(acc[mi][ni][3] + bi);
        *(ushort4*)&Sbuf[col*136 + row] = pk;
      }
    __syncthreads();
#pragma unroll
    for (int kk = 0; kk < 8; kk++) {
      int ci = kk*256 + tid;
      int r2 = ci >> 4, c2 = (ci & 15) * 8;  // r2 = e-col 0..127, c2 = b start
      int cg = (n0 - 1536) + r2;
      int h = cg >> 6, hd = cg & 63;
      *(uint4*)&vTo[((size_t)(t*H_ + h)*HD_ + hd)*B_ + (m0 & 511) + c2] =
          *(const uint4*)&Sbuf[r2*136 + c2];
    }
  }
}

// ---- Out projection -> bf16, repack epilogue. XCD-swizzled. ----
__global__ __launch_bounds__(256) void k_gemm_out(
    const unsigned short* __restrict__ A,    // [32768,768] bf16 (ctx)
    const unsigned short* __restrict__ Bw,   // [768,768] bf16
    const float* __restrict__ bias,          // [768]
    unsigned short* __restrict__ outb)       // [32768,768] bf16
{
  __shared__ __align__(16) unsigned short Sbuf[128*136];
  const int tid = threadIdx.x;
  const int bb = blockIdx.x;                 // 1536 blocks
  const int xcd = bb & 7, idx = bb >> 3;     // idx in [0,192)
  const int m0 = (xcd*32 + idx/6) * 128;
  const int n0 = (idx%6) * 128;
  GEMM_BODY(A, Bw)
  EPILOG_REPACK(bias[n0 + col])
#pragma unroll
  for (int kk = 0; kk < 8; kk++) {
    int ci = kk*256 + tid;
    int r2 = ci >> 4, c2 = (ci & 15) * 8;
    *(uint4*)&outb[(size_t)(m0 + r2)*768 + n0 + c2] = *(const uint4*)&Sbuf[r2*136 + c2];
  }
}

// ---- MFMA attention: 256-thread blocks, wave owns 32 q-rows (2 subtiles).
// 32 MFMAs per wave between barrier pairs. Block = (t,h, 128 q-rows). XCD-swizzled.
__global__ __launch_bounds__(256) void k_attn(
    const unsigned short* __restrict__ q,    // [T,H,B,HD]
    const unsigned short* __restrict__ k,    // [T,H,B,HD]
    const unsigned short* __restrict__ vT,   // [T,H,HD,B]
    unsigned short* __restrict__ ctx)        // [T,B,D]
{
  __shared__ __align__(16) unsigned short Ks[64*64];   // packed, chunk c^(r&7)
  __shared__ __align__(16) unsigned short VT[64*64];   // packed, chunk c^(r&7)
  __shared__ __align__(16) unsigned short Ps[4*32*72]; // per-wave P (32 rows), col^16quad swizzle
  const int tid = threadIdx.x;
  const int lane = tid & 63, wave = tid >> 6;          // wave 0..3
  const int ln = lane & 15, quad = lane >> 4;
  const int bb = blockIdx.x;                 // 3072 blocks
  const int xcd = bb & 7, idx = bb >> 3;     // idx in [0,384)
  const int th = xcd*96 + (idx >> 2);        // t*12+h ; th's 4 blocks share XCD
  const int q0 = (idx & 3) * 128;
  const int t = th / H_, h = th - t*H_;
  const size_t base  = (size_t)th * (B_*HD_);   // q,k base
  const size_t baseT = (size_t)th * (HD_*B_);   // vT base

  // Q fragments: this wave's 32 q-rows (2 subtiles of 16), A-layout, in registers
  short8 qf[2][2];
#pragma unroll
  for (int s = 0; s < 2; s++) {
    const unsigned short* qp = &q[base + (size_t)(q0 + wave*32 + s*16 + ln)*HD_ + quad*8];
    qf[s][0] = *(const short8*)qp;
    qf[s][1] = *(const short8*)(qp + 32);
  }
  f32x4 acc[2][4] = {};          // [q-subtile][dim-subtile], rows quad*4+r, col ln
  float dpart[2][4] = {};
  unsigned short* Pw = &Ps[wave*32*72];

  for (int kt = 0; kt < B_; kt += 64) {
    __syncthreads();
    // async-stage K chunk [64 keys][64 dims] and V^T chunk [64 dims][64 keys]
#pragma unroll
    for (int it = 0; it < 2; it++) {
      int s = it*256 + tid;
      int r = s >> 3, cp = s & 7, c = cp ^ (r & 7);
      load_lds16(&k[base + (size_t)(kt + r)*HD_ + c*8], &Ks[s*8]);
      load_lds16(&vT[baseT + (size_t)r*B_ + kt + c*8], &VT[s*8]);
    }
    __syncthreads();
    // QK^T: 4 key-subtiles x 2 q-subtiles, K-dim 64 = 2 MFMAs each
    f32x4 sf[2][4] = {};
#pragma unroll
    for (int ki = 0; ki < 4; ki++) {
      int row = ki*16 + ln;
      short8 b0 = *(const short8*)&Ks[row*64 + (quad     ^ (row & 7))*8];
      short8 b1 = *(const short8*)&Ks[row*64 + ((4+quad) ^ (row & 7))*8];
#pragma unroll
      for (int s = 0; s < 2; s++) {
        sf[s][ki] = __builtin_amdgcn_mfma_f32_16x16x32_bf16(qf[s][0], b0, sf[s][ki], 0, 0, 0);
        sf[s][ki] = __builtin_amdgcn_mfma_f32_16x16x32_bf16(qf[s][1], b1, sf[s][ki], 0, 0, 0);
      }
    }
    // exp (fp32), denominator, P to wave-local LDS
#pragma unroll
    for (int s = 0; s < 2; s++)
#pragma unroll
      for (int ki = 0; ki < 4; ki++) {
        int colbase = (ki*16 + ln) ^ (quad*16);
#pragma unroll
        for (int r = 0; r < 4; r++) {
          float p = __expf(sf[s][ki][r] * 0.125f);   // 1/sqrt(64)
          dpart[s][r] += p;
          Pw[(s*16 + quad*4 + r)*72 + colbase] = f2b(p);
        }
      }
    // PV: A-frags from Pw (row=s*16+ln, keys hf*32+quad*8+j, unswizzle ^16*((ln>>2)&3))
    short8 pa[2][2];
#pragma unroll
    for (int s = 0; s < 2; s++)
#pragma unroll
      for (int hf = 0; hf < 2; hf++) {
        int cc = (hf*32 + quad*8) ^ (16*((ln >> 2) & 3));
        pa[s][hf] = *(const short8*)&Pw[(s*16 + ln)*72 + cc];
      }
#pragma unroll
    for (int ds = 0; ds < 4; ds++) {
      int row = ds*16 + ln;                  // dim
      short8 vb0 = *(const short8*)&VT[row*64 + (quad     ^ (row & 7))*8];
      short8 vb1 = *(const short8*)&VT[row*64 + ((4+quad) ^ (row & 7))*8];
#pragma unroll
      for (int s = 0; s < 2; s++) {
        acc[s][ds] = __builtin_amdgcn_mfma_f32_16x16x32_bf16(pa[s][0], vb0, acc[s][ds], 0, 0, 0);
        acc[s][ds] = __builtin_amdgcn_mfma_f32_16x16x32_bf16(pa[s][1], vb1, acc[s][ds], 0, 0, 0);
      }
    }
  }
  // denominator: sum over 16-lane column group; write ctx [T,B,D] bf16
#pragma unroll
  for (int s = 0; s < 2; s++) {
#pragma unroll
    for (int r = 0; r < 4; r++) {
      float d = dpart[s][r];
      d += __shfl_xor(d, 1); d += __shfl_xor(d, 2);
      d += __shfl_xor(d, 4); d += __shfl_xor(d, 8);
      dpart[s][r] = 1.f / d;
    }
    int qrow = q0 + wave*32 + s*16 + quad*4;
#pragma unroll
    for (int r = 0; r < 4; r++) {
      size_t o = ((size_t)t*B_ + (qrow + r))*D_ + h*HD_ + ln;
#pragma unroll
      for (int ds = 0; ds < 4; ds++)
        ctx[o + ds*16] = f2b(acc[s][ds][r] * dpart[s][r]);
    }
  }
}

// ---- Norms + partial mean-normalized vectors (bf16 input). 512 blocks. ----
__global__ __launch_bounds__(256) void k_norms1(const unsigned short* __restrict__ outb,
                                                float* __restrict__ norms,
                                                float* __restrict__ pmvec)
{
  __shared__ float wsum[4*768];
  int blk = blockIdx.x;            // t*8 + c
  int t = blk >> 3, c = blk & 7;
  int wave = threadIdx.x >> 6, lane = threadIdx.x & 63;
  float macc[12];
#pragma unroll
  for (int j = 0; j < 12; j++) macc[j] = 0.f;
  for (int i = 0; i < 16; i++) {
    int b = c*64 + wave*16 + i;
    const unsigned short* row = &outb[((size_t)t*B_ + b)*D_];
    float x[12]; float ss = 0.f;
#pragma unroll
    for (int j = 0; j < 12; j++) { x[j] = b2f(row[lane + 64*j]); ss += x[j]*x[j]; }
#pragma unroll
    for (int off = 32; off; off >>= 1) ss += __shfl_xor(ss, off);
    float nr = fmaxf(sqrtf(ss), 1e-8f);
    if (lane == 0) norms[(size_t)t*B_ + b] = nr;
    float inv = 1.f / nr;
#pragma unroll
    for (int j = 0; j < 12; j++) macc[j] += x[j]*inv;
  }
#pragma unroll
  for (int j = 0; j < 12; j++) wsum[wave*768 + 64*j + lane] = macc[j];
  __syncthreads();
  for (int d = threadIdx.x; d < 768; d += 256) {
    pmvec[(size_t)blk*768 + d] = wsum[d] + wsum[768 + d] + wsum[1536 + d] + wsum[2304 + d];
  }
}

// ---- reduce 8 partials -> mvec[t] ----
__global__ __launch_bounds__(256) void k_norms2(const float* __restrict__ pmvec,
                                                float* __restrict__ mvec)
{
  int t = blockIdx.x;
  for (int d = threadIdx.x; d < 768; d += 256) {
    float s = 0.f;
#pragma unroll
    for (int c = 0; c < 8; c++) s += pmvec[(size_t)(t*8 + c)*768 + d];
    mvec[t*768 + d] = s * (1.0f/512.0f);
  }
}

// ---- adj[t,b] = mvec[t] . out[t,b] / norms[t,b]. One wave per row (bf16 input). ----
__global__ __launch_bounds__(256) void k_adj(const unsigned short* __restrict__ outb,
                                             const float* __restrict__ norms,
                                             const float* __restrict__ mvec,
                                             float* __restrict__ adj)
{
  int idx = blockIdx.x*4 + (threadIdx.x >> 6);   // 0..32767
  int lane = threadIdx.x & 63;
  int t = idx >> 9;
  const unsigned short* row = &outb[(size_t)idx*768];
  const float* m = &mvec[t*768];
  float dot = 0.f;
#pragma unroll
  for (int j = 0; j < 12; j++) dot += b2f(row[lane + 64*j]) * m[lane + 64*j];
#pragma unroll
  for (int off = 32; off; off >>= 1) dot += __shfl_xor(dot, off);
  if (lane == 0) adj[idx] = dot / norms[idx];
}

extern "C" void kernel_launch(void* const* d_in, const int* in_sizes, int n_in,
                              void* d_out, int out_size, void* d_ws, size_t ws_size,
                              hipStream_t stream)
{
  const float* node = (const float*)d_in[0];  // (64,512,768)
  const float* wqkv = (const float*)d_in[1];  // (2304,768)
  const float* bqkv = (const float*)d_in[2];  // (2304,)
  const float* wout = (const float*)d_in[3];  // (768,768)
  const float* bout = (const float*)d_in[4];  // (768,)
  float* adj = (float*)d_out;                 // (64,512,1)

  char* ws = (char*)d_ws;
  const size_t SZ = (size_t)M1*D_*2;          // 50,331,648 B (one bf16 [32768,768] buf)
  // Layout (~245 MiB). out_bf (48 MiB) aliases q (dead after attn).
  // pmvec (1.5 MiB) aliases x_bf (dead after qkv gemm).
  unsigned short* q_bf    = (unsigned short*)(ws);
  unsigned short* k_bf    = (unsigned short*)(ws + SZ);
  unsigned short* vT_bf   = (unsigned short*)(ws + 2*SZ);
  unsigned short* ctx_bf  = (unsigned short*)(ws + 3*SZ);
  unsigned short* x_bf    = (unsigned short*)(ws + 4*SZ);
  unsigned short* wqkv_bf = (unsigned short*)(ws + 5*SZ);
  unsigned short* wout_bf = (unsigned short*)(ws + 5*SZ + 3538944);
  unsigned short* out_bf  = (unsigned short*)(ws);                          // alias q
  float* pmvec            = (float*)(ws + 4*SZ);                            // alias x_bf
  float* norms            = (float*)(ws + 5*SZ + 3538944 + 1179648);
  float* mvec             = (float*)(ws + 5*SZ + 3538944 + 1179648 + 131072);

  // 1) fused casts to bf16
  k_cast_all<<<26880, 256, 0, stream>>>(node, wqkv, wout, x_bf, wqkv_bf, wout_bf);
  // 2) QKV projection (XCD-swizzled, LDS-repack coalesced epilogues)
  k_gemm_qkv<<<4608, 256, 0, stream>>>(x_bf, wqkv_bf, bqkv, q_bf, k_bf, vT_bf);
  // 3) attention (32 q-rows/wave, XCD-swizzled)
  k_attn<<<3072, 256, 0, stream>>>(q_bf, k_bf, vT_bf, ctx_bf);
  // 4) out projection (LDS-repack epilogue) -> bf16 out (aliases q space)
  k_gemm_out<<<1536, 256, 0, stream>>>(ctx_bf, wout_bf, bout, out_bf);
  // 5) norms + mean normalized vector per t (512-block partial + reduce)
  k_norms1<<<T_*8, 256, 0, stream>>>(out_bf, norms, pmvec);
  k_norms2<<<T_, 256, 0, stream>>>(pmvec, mvec);
  // 6) adj = mvec . xn
  k_adj<<<M1/4, 256, 0, stream>>>(out_bf, norms, mvec, adj);
}

// Round 11
// 454.190 us; speedup vs baseline: 1.2860x; 1.0112x over previous
//
#include <hip/hip_runtime.h>

// Problem constants
#define T_ 64
#define B_ 512
#define D_ 768
#define H_ 12
#define HD_ 64
#define M1 (T_*B_)        // 32768 rows for both GEMMs
#define N_QKV (3*D_)      // 2304

typedef __attribute__((ext_vector_type(8))) short short8;
typedef __attribute__((ext_vector_type(4))) float f32x4;

__device__ __forceinline__ unsigned short f2b(float f) {
  unsigned int u = __float_as_uint(f);
  u = (u + 0x7FFFu + ((u >> 16) & 1u)) >> 16;   // RNE
  return (unsigned short)u;
}
__device__ __forceinline__ float b2f(unsigned short s) {
  return __uint_as_float(((unsigned int)s) << 16);
}

// async 16B global -> LDS (wave-uniform LDS base + lane*16 scatter semantics)
__device__ __forceinline__ void load_lds16(const unsigned short* g, unsigned short* l) {
  __builtin_amdgcn_global_load_lds(
      (const __attribute__((address_space(1))) unsigned int*)g,
      (__attribute__((address_space(3))) unsigned int*)l, 16, 0, 0);
}

// ---- fused fp32 -> bf16 casts (node / wqkv / wout in one launch) ----
#define N4_NODE 6291456
#define N4_WQKV 442368
#define N4_WOUT 147456
__global__ __launch_bounds__(256) void k_cast_all(
    const float* __restrict__ node, const float* __restrict__ wqkv,
    const float* __restrict__ wout, unsigned short* __restrict__ x_bf,
    unsigned short* __restrict__ wqkv_bf, unsigned short* __restrict__ wout_bf) {
  int i = blockIdx.x * 256 + threadIdx.x;
  const float* src; unsigned short* dst; int off;
  if (i < N4_NODE)                 { src = node; dst = x_bf;    off = i; }
  else if (i < N4_NODE + N4_WQKV)  { src = wqkv; dst = wqkv_bf; off = i - N4_NODE; }
  else                             { src = wout; dst = wout_bf; off = i - N4_NODE - N4_WQKV; }
  float4 v = ((const float4*)src)[off];
  ushort4 o;
  o.x = f2b(v.x); o.y = f2b(v.y); o.z = f2b(v.z); o.w = f2b(v.w);
  ((ushort4*)dst)[off] = o;
}

// ============ GEMM core (128x128 tile, BK=64, global_load_lds + XOR swizzle) ============
// LDS packed [row][64 shorts], 16B chunk (row,c) at slot c^(row&7).
// Staging conflict-free; fragment reads 2-way aliased (free per m136).
#define GEMM_BODY(Aptr, Bptr) \
  unsigned short* As = Sbuf; \
  unsigned short* Bs = Sbuf + 8192; \
  const int lane = tid & 63, wave = tid >> 6; \
  const int ln = lane & 15, quad = lane >> 4; \
  const int wm = (wave & 1) * 64, wn = (wave >> 1) * 64; \
  f32x4 acc[4][4] = {}; \
  for (int k0 = 0; k0 < 768; k0 += 64) { \
    __syncthreads(); \
    _Pragma("unroll") \
    for (int it = 0; it < 4; it++) { \
      int s = wave*256 + it*64 + lane; \
      int r = s >> 3, cp = s & 7, c = cp ^ (r & 7); \
      load_lds16(&Aptr[(size_t)(m0+r)*768 + k0 + c*8], &As[s*8]); \
      load_lds16(&Bptr[(size_t)(n0+r)*768 + k0 + c*8], &Bs[s*8]); \
    } \
    __syncthreads(); \
    _Pragma("unroll") \
    for (int j = 0; j < 2; j++) { \
      short8 a[4], b[4]; \
      _Pragma("unroll") \
      for (int i = 0; i < 4; i++) { \
        int row = wm + i*16 + ln; \
        int cp = (j*4 + quad) ^ (row & 7); \
        a[i] = *(const short8*)&As[row*64 + cp*8]; \
      } \
      _Pragma("unroll") \
      for (int i = 0; i < 4; i++) { \
        int row = wn + i*16 + ln; \
        int cp = (j*4 + quad) ^ (row & 7); \
        b[i] = *(const short8*)&Bs[row*64 + cp*8]; \
      } \
      _Pragma("unroll") \
      for (int mi = 0; mi < 4; mi++) \
        _Pragma("unroll") \
        for (int ni = 0; ni < 4; ni++) \
          acc[mi][ni] = __builtin_amdgcn_mfma_f32_16x16x32_bf16(a[mi], b[ni], acc[mi][ni], 0, 0, 0); \
    } \
  }

// Repack acc (+bias per column) into Sbuf as [row 0..127][col 0..127], stride 136.
#define EPILOG_REPACK(BIASEXPR) \
  __syncthreads(); \
  _Pragma("unroll") \
  for (int ni = 0; ni < 4; ni++) { \
    int col = wn + ni*16 + ln; \
    float bi = (BIASEXPR); \
    _Pragma("unroll") \
    for (int mi = 0; mi < 4; mi++) { \
      int row = wm + mi*16 + quad*4; \
      _Pragma("unroll") \
      for (int r = 0; r < 4; r++) \
        Sbuf[(row + r)*136 + col] = f2b(acc[mi][ni][r] + bi); \
    } \
  } \
  __syncthreads();

// ---- QKV projection. XCD-swizzled. All epilogues repack through LDS -> coalesced 16B stores.
__global__ __launch_bounds__(256) void k_gemm_qkv(
    const unsigned short* __restrict__ A,    // [32768,768] bf16
    const unsigned short* __restrict__ Bw,   // [2304,768]  bf16
    const float* __restrict__ bias,          // [2304]
    unsigned short* __restrict__ qo,
    unsigned short* __restrict__ ko,
    unsigned short* __restrict__ vTo)
{
  __shared__ __align__(16) unsigned short Sbuf[128*136];  // K-loop uses first 32 KB
  const int tid = threadIdx.x;
  const int bb = blockIdx.x;                 // 4608 blocks
  const int xcd = bb & 7, idx = bb >> 3;     // idx in [0,576)
  const int m0 = (xcd*32 + idx/18) * 128;    // same-XCD blocks share m-stripe
  const int n0 = (idx%18) * 128;             // n sweeps fastest -> A-tile L2 reuse
  GEMM_BODY(A, Bw)
  const int t = m0 >> 9;

  if (n0 < 1536) {
    // ---- q/k: repack [b-row][e-col] then stream coalesced into [T,H,B,HD] ----
    EPILOG_REPACK(bias[n0 + col])
    unsigned short* dst = (n0 < 768) ? qo : ko;
    const int colbase = (n0 < 768) ? n0 : (n0 - 768);
#pragma unroll
    for (int kk = 0; kk < 8; kk++) {
      int ci = kk*256 + tid;                 // 2048 chunks of 8 shorts
      int r2 = ci >> 4, c2 = (ci & 15) * 8;  // row 0..127, col start
      int within = colbase + c2;
      int h = within >> 6, hd = within & 63;
      *(uint4*)&dst[((size_t)(t*H_ + h)*B_ + (m0 & 511) + r2)*HD_ + hd] =
          *(const uint4*)&Sbuf[r2*136 + c2];
    }
  } else {
    // ---- v: repack transposed [e-col][b-row] then stream coalesced into [T,H,HD,B] ----
    __syncthreads();
#pragma unroll
    for (int mi = 0; mi < 4; mi++)
#pragma unroll
      for (int ni = 0; ni < 4; ni++) {
        int col = wn + ni*16 + ln;
        int row = wm + mi*16 + quad*4;
        float bi = bias[n0 + col];
        ushort4 pk;
        pk.x = f2b(acc[mi][ni][0] + bi);
        pk.y = f2b(acc[mi][ni][1] + bi);
        pk.z = f2b(acc[mi][ni][2] + bi);
        pk.w = f2b(acc[mi][ni][3] + bi);
        *(ushort4*)&Sbuf[col*136 + row] = pk;
      }
    __syncthreads();
#pragma unroll
    for (int kk = 0; kk < 8; kk++) {
      int ci = kk*256 + tid;
      int r2 = ci >> 4, c2 = (ci & 15) * 8;  // r2 = e-col 0..127, c2 = b start
      int cg = (n0 - 1536) + r2;
      int h = cg >> 6, hd = cg & 63;
      *(uint4*)&vTo[((size_t)(t*H_ + h)*HD_ + hd)*B_ + (m0 & 511) + c2] =
          *(const uint4*)&Sbuf[r2*136 + c2];
    }
  }
}

// ---- Out projection -> bf16, repack epilogue. XCD-swizzled. ----
__global__ __launch_bounds__(256) void k_gemm_out(
    const unsigned short* __restrict__ A,    // [32768,768] bf16 (ctx)
    const unsigned short* __restrict__ Bw,   // [768,768] bf16
    const float* __restrict__ bias,          // [768]
    unsigned short* __restrict__ outb)       // [32768,768] bf16
{
  __shared__ __align__(16) unsigned short Sbuf[128*136];
  const int tid = threadIdx.x;
  const int bb = blockIdx.x;                 // 1536 blocks
  const int xcd = bb & 7, idx = bb >> 3;     // idx in [0,192)
  const int m0 = (xcd*32 + idx/6) * 128;
  const int n0 = (idx%6) * 128;
  GEMM_BODY(A, Bw)
  EPILOG_REPACK(bias[n0 + col])
#pragma unroll
  for (int kk = 0; kk < 8; kk++) {
    int ci = kk*256 + tid;
    int r2 = ci >> 4, c2 = (ci & 15) * 8;
    *(uint4*)&outb[(size_t)(m0 + r2)*768 + n0 + c2] = *(const uint4*)&Sbuf[r2*136 + c2];
  }
}

// ---- MFMA attention, softmax-VALU-optimized:
// QK^T SWAPPED (mfma(K_frag, Q_frag) -> S^T: acc regs span KEYS) so P-writes are
// 4 contiguous shorts (2 pack ops + ds_write_b64, truncation rounding) and the
// denominator reduces with 2 shuffles/subtile once at the end (LDS transpose for
// the divide). PV unchanged. P column swizzle ^8*(ln>>2) keeps reads <=3-way.
__global__ __launch_bounds__(256) void k_attn(
    const unsigned short* __restrict__ q,    // [T,H,B,HD]
    const unsigned short* __restrict__ k,    // [T,H,B,HD]
    const unsigned short* __restrict__ vT,   // [T,H,HD,B]
    unsigned short* __restrict__ ctx)        // [T,B,D]
{
  __shared__ __align__(16) unsigned short Ks[64*64];   // packed, chunk c^(r&7)
  __shared__ __align__(16) unsigned short VT[64*64];   // packed, chunk c^(r&7)
  __shared__ __align__(16) unsigned short Ps[4*32*72]; // per-wave P[qrow][key^swz]
  __shared__ float Dn[4*64];                           // per-wave denominators
  const int tid = threadIdx.x;
  const int lane = tid & 63, wave = tid >> 6;          // wave 0..3
  const int ln = lane & 15, quad = lane >> 4;
  const int pxr = 8 * (ln >> 2);                       // P column XOR swizzle
  const int bb = blockIdx.x;                 // 3072 blocks
  const int xcd = bb & 7, idx = bb >> 3;     // idx in [0,384)
  const int th = xcd*96 + (idx >> 2);        // t*12+h ; th's 4 blocks share XCD
  const int q0 = (idx & 3) * 128;
  const int t = th / H_, h = th - t*H_;
  const size_t base  = (size_t)th * (B_*HD_);   // q,k base
  const size_t baseT = (size_t)th * (HD_*B_);   // vT base

  // Q fragments: this wave's 32 q-rows (2 subtiles of 16), in registers.
  // (Same register content serves as B-operand for the swapped QK^T.)
  short8 qf[2][2];
#pragma unroll
  for (int s = 0; s < 2; s++) {
    const unsigned short* qp = &q[base + (size_t)(q0 + wave*32 + s*16 + ln)*HD_ + quad*8];
    qf[s][0] = *(const short8*)qp;
    qf[s][1] = *(const short8*)(qp + 32);
  }
  f32x4 acc[2][4] = {};          // [q-subtile][dim-subtile], rows=qrow quad*4+r, col=dim ln
  float dpart[2] = {0.f, 0.f};   // per-lane partial denominators (qrow = s*16+ln)
  unsigned short* Pw = &Ps[wave*32*72];

  for (int kt = 0; kt < B_; kt += 64) {
    __syncthreads();
    // async-stage K chunk [64 keys][64 dims] and V^T chunk [64 dims][64 keys]
#pragma unroll
    for (int it = 0; it < 2; it++) {
      int s = it*256 + tid;
      int r = s >> 3, cp = s & 7, c = cp ^ (r & 7);
      load_lds16(&k[base + (size_t)(kt + r)*HD_ + c*8], &Ks[s*8]);
      load_lds16(&vT[baseT + (size_t)r*B_ + kt + c*8], &VT[s*8]);
    }
    __syncthreads();
    // QK^T swapped: sf[s][ki] = S^T rows=key(ki*16+quad*4+r), col=qrow(s*16+ln)
    f32x4 sf[2][4] = {};
#pragma unroll
    for (int ki = 0; ki < 4; ki++) {
      int row = ki*16 + ln;
      short8 kf0 = *(const short8*)&Ks[row*64 + (quad     ^ (row & 7))*8];
      short8 kf1 = *(const short8*)&Ks[row*64 + ((4+quad) ^ (row & 7))*8];
#pragma unroll
      for (int s = 0; s < 2; s++) {
        sf[s][ki] = __builtin_amdgcn_mfma_f32_16x16x32_bf16(kf0, qf[s][0], sf[s][ki], 0, 0, 0);
        sf[s][ki] = __builtin_amdgcn_mfma_f32_16x16x32_bf16(kf1, qf[s][1], sf[s][ki], 0, 0, 0);
      }
    }
    // exp (fp32), lane-local denominator, truncate-pack 4 keys -> ds_write_b64
#pragma unroll
    for (int s = 0; s < 2; s++)
#pragma unroll
      for (int ki = 0; ki < 4; ki++) {
        float p0 = __expf(sf[s][ki][0] * 0.125f);
        float p1 = __expf(sf[s][ki][1] * 0.125f);
        float p2 = __expf(sf[s][ki][2] * 0.125f);
        float p3 = __expf(sf[s][ki][3] * 0.125f);
        dpart[s] += (p0 + p1) + (p2 + p3);
        uint2 uu;
        uu.x = (__float_as_uint(p1) & 0xFFFF0000u) | (__float_as_uint(p0) >> 16);
        uu.y = (__float_as_uint(p3) & 0xFFFF0000u) | (__float_as_uint(p2) >> 16);
        int col = (ki*16 + quad*4) ^ pxr;
        *(uint2*)&Pw[(s*16 + ln)*72 + col] = uu;
      }
    // PV: A-frags from Pw[qrow][keys], B-frags from VT packed chunks
    short8 pa[2][2];
#pragma unroll
    for (int s = 0; s < 2; s++)
#pragma unroll
      for (int hf = 0; hf < 2; hf++)
        pa[s][hf] = *(const short8*)&Pw[(s*16 + ln)*72 + ((hf*32 + quad*8) ^ pxr)];
#pragma unroll
    for (int ds = 0; ds < 4; ds++) {
      int row = ds*16 + ln;                  // dim
      short8 vb0 = *(const short8*)&VT[row*64 + (quad     ^ (row & 7))*8];
      short8 vb1 = *(const short8*)&VT[row*64 + ((4+quad) ^ (row & 7))*8];
#pragma unroll
      for (int s = 0; s < 2; s++) {
        acc[s][ds] = __builtin_amdgcn_mfma_f32_16x16x32_bf16(pa[s][0], vb0, acc[s][ds], 0, 0, 0);
        acc[s][ds] = __builtin_amdgcn_mfma_f32_16x16x32_bf16(pa[s][1], vb1, acc[s][ds], 0, 0, 0);
      }
    }
  }
  // denominators: reduce over quad groups (2 shuffles), stash in LDS for the divide
#pragma unroll
  for (int s = 0; s < 2; s++) {
    float d = dpart[s];
    d += __shfl_xor(d, 16);
    d += __shfl_xor(d, 32);
    if (quad == 0) Dn[wave*64 + s*16 + ln] = d;
  }
  // write ctx [T,B,D] bf16 (DS ops in-order per wave: Dn visible without barrier)
#pragma unroll
  for (int s = 0; s < 2; s++) {
    int qrow = q0 + wave*32 + s*16 + quad*4;
#pragma unroll
    for (int r = 0; r < 4; r++) {
      float invd = 1.f / Dn[wave*64 + s*16 + quad*4 + r];
      size_t o = ((size_t)t*B_ + (qrow + r))*D_ + h*HD_ + ln;
#pragma unroll
      for (int ds = 0; ds < 4; ds++)
        ctx[o + ds*16] = f2b(acc[s][ds][r] * invd);
    }
  }
}

// ---- Norms + partial mean-normalized vectors (bf16 input). 512 blocks. ----
__global__ __launch_bounds__(256) void k_norms1(const unsigned short* __restrict__ outb,
                                                float* __restrict__ norms,
                                                float* __restrict__ pmvec)
{
  __shared__ float wsum[4*768];
  int blk = blockIdx.x;            // t*8 + c
  int t = blk >> 3, c = blk & 7;
  int wave = threadIdx.x >> 6, lane = threadIdx.x & 63;
  float macc[12];
#pragma unroll
  for (int j = 0; j < 12; j++) macc[j] = 0.f;
  for (int i = 0; i < 16; i++) {
    int b = c*64 + wave*16 + i;
    const unsigned short* row = &outb[((size_t)t*B_ + b)*D_];
    float x[12]; float ss = 0.f;
#pragma unroll
    for (int j = 0; j < 12; j++) { x[j] = b2f(row[lane + 64*j]); ss += x[j]*x[j]; }
#pragma unroll
    for (int off = 32; off; off >>= 1) ss += __shfl_xor(ss, off);
    float nr = fmaxf(sqrtf(ss), 1e-8f);
    if (lane == 0) norms[(size_t)t*B_ + b] = nr;
    float inv = 1.f / nr;
#pragma unroll
    for (int j = 0; j < 12; j++) macc[j] += x[j]*inv;
  }
#pragma unroll
  for (int j = 0; j < 12; j++) wsum[wave*768 + 64*j + lane] = macc[j];
  __syncthreads();
  for (int d = threadIdx.x; d < 768; d += 256) {
    pmvec[(size_t)blk*768 + d] = wsum[d] + wsum[768 + d] + wsum[1536 + d] + wsum[2304 + d];
  }
}

// ---- reduce 8 partials -> mvec[t] ----
__global__ __launch_bounds__(256) void k_norms2(const float* __restrict__ pmvec,
                                                float* __restrict__ mvec)
{
  int t = blockIdx.x;
  for (int d = threadIdx.x; d < 768; d += 256) {
    float s = 0.f;
#pragma unroll
    for (int c = 0; c < 8; c++) s += pmvec[(size_t)(t*8 + c)*768 + d];
    mvec[t*768 + d] = s * (1.0f/512.0f);
  }
}

// ---- adj[t,b] = mvec[t] . out[t,b] / norms[t,b]. One wave per row (bf16 input). ----
__global__ __launch_bounds__(256) void k_adj(const unsigned short* __restrict__ outb,
                                             const float* __restrict__ norms,
                                             const float* __restrict__ mvec,
                                             float* __restrict__ adj)
{
  int idx = blockIdx.x*4 + (threadIdx.x >> 6);   // 0..32767
  int lane = threadIdx.x & 63;
  int t = idx >> 9;
  const unsigned short* row = &outb[(size_t)idx*768];
  const float* m = &mvec[t*768];
  float dot = 0.f;
#pragma unroll
  for (int j = 0; j < 12; j++) dot += b2f(row[lane + 64*j]) * m[lane + 64*j];
#pragma unroll
  for (int off = 32; off; off >>= 1) dot += __shfl_xor(dot, off);
  if (lane == 0) adj[idx] = dot / norms[idx];
}

extern "C" void kernel_launch(void* const* d_in, const int* in_sizes, int n_in,
                              void* d_out, int out_size, void* d_ws, size_t ws_size,
                              hipStream_t stream)
{
  const float* node = (const float*)d_in[0];  // (64,512,768)
  const float* wqkv = (const float*)d_in[1];  // (2304,768)
  const float* bqkv = (const float*)d_in[2];  // (2304,)
  const float* wout = (const float*)d_in[3];  // (768,768)
  const float* bout = (const float*)d_in[4];  // (768,)
  float* adj = (float*)d_out;                 // (64,512,1)

  char* ws = (char*)d_ws;
  const size_t SZ = (size_t)M1*D_*2;          // 50,331,648 B (one bf16 [32768,768] buf)
  // Layout (~245 MiB). out_bf (48 MiB) aliases q (dead after attn).
  // pmvec (1.5 MiB) aliases x_bf (dead after qkv gemm).
  unsigned short* q_bf    = (unsigned short*)(ws);
  unsigned short* k_bf    = (unsigned short*)(ws + SZ);
  unsigned short* vT_bf   = (unsigned short*)(ws + 2*SZ);
  unsigned short* ctx_bf  = (unsigned short*)(ws + 3*SZ);
  unsigned short* x_bf    = (unsigned short*)(ws + 4*SZ);
  unsigned short* wqkv_bf = (unsigned short*)(ws + 5*SZ);
  unsigned short* wout_bf = (unsigned short*)(ws + 5*SZ + 3538944);
  unsigned short* out_bf  = (unsigned short*)(ws);                          // alias q
  float* pmvec            = (float*)(ws + 4*SZ);                            // alias x_bf
  float* norms            = (float*)(ws + 5*SZ + 3538944 + 1179648);
  float* mvec             = (float*)(ws + 5*SZ + 3538944 + 1179648 + 131072);

  // 1) fused casts to bf16
  k_cast_all<<<26880, 256, 0, stream>>>(node, wqkv, wout, x_bf, wqkv_bf, wout_bf);
  // 2) QKV projection (XCD-swizzled, LDS-repack coalesced epilogues)
  k_gemm_qkv<<<4608, 256, 0, stream>>>(x_bf, wqkv_bf, bqkv, q_bf, k_bf, vT_bf);
  // 3) attention (swapped QK^T, packed P-writes, XCD-swizzled)
  k_attn<<<3072, 256, 0, stream>>>(q_bf, k_bf, vT_bf, ctx_bf);
  // 4) out projection (LDS-repack epilogue) -> bf16 out (aliases q space)
  k_gemm_out<<<1536, 256, 0, stream>>>(ctx_bf, wout_bf, bout, out_bf);
  // 5) norms + mean normalized vector per t (512-block partial + reduce)
  k_norms1<<<T_*8, 256, 0, stream>>>(out_bf, norms, pmvec);
  k_norms2<<<T_, 256, 0, stream>>>(pmvec, mvec);
  // 6) adj = mvec . xn
  k_adj<<<M1/4, 256, 0, stream>>>(out_bf, norms, mvec, adj);
}

// Round 12
// 446.327 us; speedup vs baseline: 1.3087x; 1.0176x over previous
//
#include <hip/hip_runtime.h>

// Problem constants
#define T_ 64
#define B_ 512
#define D_ 768
#define H_ 12
#define HD_ 64
#define M1 (T_*B_)        // 32768 rows for both GEMMs
#define N_QKV (3*D_)      // 2304

typedef __attribute__((ext_vector_type(8))) short short8;
typedef __attribute__((ext_vector_type(4))) float f32x4;

__device__ __forceinline__ unsigned short f2b(float f) {
  unsigned int u = __float_as_uint(f);
  u = (u + 0x7FFFu + ((u >> 16) & 1u)) >> 16;   // RNE
  return (unsigned short)u;
}
__device__ __forceinline__ float b2f(unsigned short s) {
  return __uint_as_float(((unsigned int)s) << 16);
}

// async 16B global -> LDS (wave-uniform LDS base + lane*16 scatter semantics)
__device__ __forceinline__ void load_lds16(const unsigned short* g, unsigned short* l) {
  __builtin_amdgcn_global_load_lds(
      (const __attribute__((address_space(1))) unsigned int*)g,
      (__attribute__((address_space(3))) unsigned int*)l, 16, 0, 0);
}

// ---- fused fp32 -> bf16 casts (node / wqkv / wout in one launch) ----
#define N4_NODE 6291456
#define N4_WQKV 442368
#define N4_WOUT 147456
__global__ __launch_bounds__(256) void k_cast_all(
    const float* __restrict__ node, const float* __restrict__ wqkv,
    const float* __restrict__ wout, unsigned short* __restrict__ x_bf,
    unsigned short* __restrict__ wqkv_bf, unsigned short* __restrict__ wout_bf) {
  int i = blockIdx.x * 256 + threadIdx.x;
  const float* src; unsigned short* dst; int off;
  if (i < N4_NODE)                 { src = node; dst = x_bf;    off = i; }
  else if (i < N4_NODE + N4_WQKV)  { src = wqkv; dst = wqkv_bf; off = i - N4_NODE; }
  else                             { src = wout; dst = wout_bf; off = i - N4_NODE - N4_WQKV; }
  float4 v = ((const float4*)src)[off];
  ushort4 o;
  o.x = f2b(v.x); o.y = f2b(v.y); o.z = f2b(v.z); o.w = f2b(v.w);
  ((ushort4*)dst)[off] = o;
}

// ============ GEMM core (128x128 tile, BK=64, global_load_lds + XOR swizzle) ============
// LDS packed [row][64 shorts], 16B chunk (row,c) at slot c^(row&7).
// Staging conflict-free; fragment reads 2-way aliased (free per m136).
#define GEMM_BODY(Aptr, Bptr) \
  unsigned short* As = Sbuf; \
  unsigned short* Bs = Sbuf + 8192; \
  const int lane = tid & 63, wave = tid >> 6; \
  const int ln = lane & 15, quad = lane >> 4; \
  const int wm = (wave & 1) * 64, wn = (wave >> 1) * 64; \
  f32x4 acc[4][4] = {}; \
  for (int k0 = 0; k0 < 768; k0 += 64) { \
    __syncthreads(); \
    _Pragma("unroll") \
    for (int it = 0; it < 4; it++) { \
      int s = wave*256 + it*64 + lane; \
      int r = s >> 3, cp = s & 7, c = cp ^ (r & 7); \
      load_lds16(&Aptr[(size_t)(m0+r)*768 + k0 + c*8], &As[s*8]); \
      load_lds16(&Bptr[(size_t)(n0+r)*768 + k0 + c*8], &Bs[s*8]); \
    } \
    __syncthreads(); \
    _Pragma("unroll") \
    for (int j = 0; j < 2; j++) { \
      short8 a[4], b[4]; \
      _Pragma("unroll") \
      for (int i = 0; i < 4; i++) { \
        int row = wm + i*16 + ln; \
        int cp = (j*4 + quad) ^ (row & 7); \
        a[i] = *(const short8*)&As[row*64 + cp*8]; \
      } \
      _Pragma("unroll") \
      for (int i = 0; i < 4; i++) { \
        int row = wn + i*16 + ln; \
        int cp = (j*4 + quad) ^ (row & 7); \
        b[i] = *(const short8*)&Bs[row*64 + cp*8]; \
      } \
      _Pragma("unroll") \
      for (int mi = 0; mi < 4; mi++) \
        _Pragma("unroll") \
        for (int ni = 0; ni < 4; ni++) \
          acc[mi][ni] = __builtin_amdgcn_mfma_f32_16x16x32_bf16(a[mi], b[ni], acc[mi][ni], 0, 0, 0); \
    } \
  }

// Repack acc (+bias per column) into Sbuf as [row 0..127][col 0..127], stride 136.
#define EPILOG_REPACK(BIASEXPR) \
  __syncthreads(); \
  _Pragma("unroll") \
  for (int ni = 0; ni < 4; ni++) { \
    int col = wn + ni*16 + ln; \
    float bi = (BIASEXPR); \
    _Pragma("unroll") \
    for (int mi = 0; mi < 4; mi++) { \
      int row = wm + mi*16 + quad*4; \
      _Pragma("unroll") \
      for (int r = 0; r < 4; r++) \
        Sbuf[(row + r)*136 + col] = f2b(acc[mi][ni][r] + bi); \
    } \
  } \
  __syncthreads();

// ---- QKV projection. XCD-swizzled. All epilogues repack through LDS -> coalesced 16B stores.
__global__ __launch_bounds__(256) void k_gemm_qkv(
    const unsigned short* __restrict__ A,    // [32768,768] bf16
    const unsigned short* __restrict__ Bw,   // [2304,768]  bf16
    const float* __restrict__ bias,          // [2304]
    unsigned short* __restrict__ qo,
    unsigned short* __restrict__ ko,
    unsigned short* __restrict__ vTo)
{
  __shared__ __align__(16) unsigned short Sbuf[128*136];  // K-loop uses first 32 KB
  const int tid = threadIdx.x;
  const int bb = blockIdx.x;                 // 4608 blocks
  const int xcd = bb & 7, idx = bb >> 3;     // idx in [0,576)
  const int m0 = (xcd*32 + idx/18) * 128;    // same-XCD blocks share m-stripe
  const int n0 = (idx%18) * 128;             // n sweeps fastest -> A-tile L2 reuse
  GEMM_BODY(A, Bw)
  const int t = m0 >> 9;

  if (n0 < 1536) {
    // ---- q/k: repack [b-row][e-col] then stream coalesced into [T,H,B,HD] ----
    EPILOG_REPACK(bias[n0 + col])
    unsigned short* dst = (n0 < 768) ? qo : ko;
    const int colbase = (n0 < 768) ? n0 : (n0 - 768);
#pragma unroll
    for (int kk = 0; kk < 8; kk++) {
      int ci = kk*256 + tid;                 // 2048 chunks of 8 shorts
      int r2 = ci >> 4, c2 = (ci & 15) * 8;  // row 0..127, col start
      int within = colbase + c2;
      int h = within >> 6, hd = within & 63;
      *(uint4*)&dst[((size_t)(t*H_ + h)*B_ + (m0 & 511) + r2)*HD_ + hd] =
          *(const uint4*)&Sbuf[r2*136 + c2];
    }
  } else {
    // ---- v: repack transposed [e-col][b-row] then stream coalesced into [T,H,HD,B] ----
    __syncthreads();
#pragma unroll
    for (int mi = 0; mi < 4; mi++)
#pragma unroll
      for (int ni = 0; ni < 4; ni++) {
        int col = wn + ni*16 + ln;
        int row = wm + mi*16 + quad*4;
        float bi = bias[n0 + col];
        ushort4 pk;
        pk.x = f2b(acc[mi][ni][0] + bi);
        pk.y = f2b(acc[mi][ni][1] + bi);
        pk.z = f2b(acc[mi][ni][2] + bi);
        pk.w = f2b(acc[mi][ni][3] + bi);
        *(ushort4*)&Sbuf[col*136 + row] = pk;
      }
    __syncthreads();
#pragma unroll
    for (int kk = 0; kk < 8; kk++) {
      int ci = kk*256 + tid;
      int r2 = ci >> 4, c2 = (ci & 15) * 8;  // r2 = e-col 0..127, c2 = b start
      int cg = (n0 - 1536) + r2;
      int h = cg >> 6, hd = cg & 63;
      *(uint4*)&vTo[((size_t)(t*H_ + h)*HD_ + hd)*B_ + (m0 & 511) + c2] =
          *(const uint4*)&Sbuf[r2*136 + c2];
    }
  }
}

// ---- Out projection -> bf16, repack epilogue. XCD-swizzled. ----
__global__ __launch_bounds__(256) void k_gemm_out(
    const unsigned short* __restrict__ A,    // [32768,768] bf16 (ctx)
    const unsigned short* __restrict__ Bw,   // [768,768] bf16
    const float* __restrict__ bias,          // [768]
    unsigned short* __restrict__ outb)       // [32768,768] bf16
{
  __shared__ __align__(16) unsigned short Sbuf[128*136];
  const int tid = threadIdx.x;
  const int bb = blockIdx.x;                 // 1536 blocks
  const int xcd = bb & 7, idx = bb >> 3;     // idx in [0,192)
  const int m0 = (xcd*32 + idx/6) * 128;
  const int n0 = (idx%6) * 128;
  GEMM_BODY(A, Bw)
  EPILOG_REPACK(bias[n0 + col])
#pragma unroll
  for (int kk = 0; kk < 8; kk++) {
    int ci = kk*256 + tid;
    int r2 = ci >> 4, c2 = (ci & 15) * 8;
    *(uint4*)&outb[(size_t)(m0 + r2)*768 + n0 + c2] = *(const uint4*)&Sbuf[r2*136 + c2];
  }
}

// ---- MFMA attention: 512-thread blocks, 2 blocks per (t,h) -> K/V staging
// redundancy halved (was 4 blocks/th). 8 waves x 32 q-rows = 256 q-rows/block.
// Swapped QK^T (S^T in regs), packed b64 P-writes, lane-local denominators.
__global__ __launch_bounds__(512) void k_attn(
    const unsigned short* __restrict__ q,    // [T,H,B,HD]
    const unsigned short* __restrict__ k,    // [T,H,B,HD]
    const unsigned short* __restrict__ vT,   // [T,H,HD,B]
    unsigned short* __restrict__ ctx)        // [T,B,D]
{
  __shared__ __align__(16) unsigned short Ks[64*64];   // packed, chunk c^(r&7)
  __shared__ __align__(16) unsigned short VT[64*64];   // packed, chunk c^(r&7)
  __shared__ __align__(16) unsigned short Ps[8*32*72]; // per-wave P[qrow][key^swz]
  __shared__ float Dn[8*64];                           // per-wave denominators
  const int tid = threadIdx.x;
  const int lane = tid & 63, wave = tid >> 6;          // wave 0..7
  const int ln = lane & 15, quad = lane >> 4;
  const int pxr = 8 * (ln >> 2);                       // P column XOR swizzle
  const int bb = blockIdx.x;                 // 1536 blocks
  const int xcd = bb & 7, idx = bb >> 3;     // idx in [0,192)
  const int th = xcd*96 + (idx >> 1);        // t*12+h ; th's 2 blocks share XCD
  const int q0 = (idx & 1) * 256;
  const int t = th / H_, h = th - t*H_;
  const size_t base  = (size_t)th * (B_*HD_);   // q,k base
  const size_t baseT = (size_t)th * (HD_*B_);   // vT base

  // Q fragments: this wave's 32 q-rows (2 subtiles of 16), in registers.
  short8 qf[2][2];
#pragma unroll
  for (int s = 0; s < 2; s++) {
    const unsigned short* qp = &q[base + (size_t)(q0 + wave*32 + s*16 + ln)*HD_ + quad*8];
    qf[s][0] = *(const short8*)qp;
    qf[s][1] = *(const short8*)(qp + 32);
  }
  f32x4 acc[2][4] = {};          // [q-subtile][dim-subtile], rows=qrow quad*4+r, col=dim ln
  float dpart[2] = {0.f, 0.f};   // per-lane partial denominators (qrow = s*16+ln)
  unsigned short* Pw = &Ps[wave*32*72];

  for (int kt = 0; kt < B_; kt += 64) {
    __syncthreads();
    // async-stage K chunk [64 keys][64 dims] and V^T chunk [64 dims][64 keys]
    // 512 threads cover all 512 16B-chunks of each buffer in one sweep
    {
      int s = tid;
      int r = s >> 3, cp = s & 7, c = cp ^ (r & 7);
      load_lds16(&k[base + (size_t)(kt + r)*HD_ + c*8], &Ks[s*8]);
      load_lds16(&vT[baseT + (size_t)r*B_ + kt + c*8], &VT[s*8]);
    }
    __syncthreads();
    // QK^T swapped: sf[s][ki] = S^T rows=key(ki*16+quad*4+r), col=qrow(s*16+ln)
    f32x4 sf[2][4] = {};
#pragma unroll
    for (int ki = 0; ki < 4; ki++) {
      int row = ki*16 + ln;
      short8 kf0 = *(const short8*)&Ks[row*64 + (quad     ^ (row & 7))*8];
      short8 kf1 = *(const short8*)&Ks[row*64 + ((4+quad) ^ (row & 7))*8];
#pragma unroll
      for (int s = 0; s < 2; s++) {
        sf[s][ki] = __builtin_amdgcn_mfma_f32_16x16x32_bf16(kf0, qf[s][0], sf[s][ki], 0, 0, 0);
        sf[s][ki] = __builtin_amdgcn_mfma_f32_16x16x32_bf16(kf1, qf[s][1], sf[s][ki], 0, 0, 0);
      }
    }
    // exp (fp32), lane-local denominator, truncate-pack 4 keys -> ds_write_b64
#pragma unroll
    for (int s = 0; s < 2; s++)
#pragma unroll
      for (int ki = 0; ki < 4; ki++) {
        float p0 = __expf(sf[s][ki][0] * 0.125f);
        float p1 = __expf(sf[s][ki][1] * 0.125f);
        float p2 = __expf(sf[s][ki][2] * 0.125f);
        float p3 = __expf(sf[s][ki][3] * 0.125f);
        dpart[s] += (p0 + p1) + (p2 + p3);
        uint2 uu;
        uu.x = (__float_as_uint(p1) & 0xFFFF0000u) | (__float_as_uint(p0) >> 16);
        uu.y = (__float_as_uint(p3) & 0xFFFF0000u) | (__float_as_uint(p2) >> 16);
        int col = (ki*16 + quad*4) ^ pxr;
        *(uint2*)&Pw[(s*16 + ln)*72 + col] = uu;
      }
    // PV: A-frags from Pw[qrow][keys], B-frags from VT packed chunks
    short8 pa[2][2];
#pragma unroll
    for (int s = 0; s < 2; s++)
#pragma unroll
      for (int hf = 0; hf < 2; hf++)
        pa[s][hf] = *(const short8*)&Pw[(s*16 + ln)*72 + ((hf*32 + quad*8) ^ pxr)];
#pragma unroll
    for (int ds = 0; ds < 4; ds++) {
      int row = ds*16 + ln;                  // dim
      short8 vb0 = *(const short8*)&VT[row*64 + (quad     ^ (row & 7))*8];
      short8 vb1 = *(const short8*)&VT[row*64 + ((4+quad) ^ (row & 7))*8];
#pragma unroll
      for (int s = 0; s < 2; s++) {
        acc[s][ds] = __builtin_amdgcn_mfma_f32_16x16x32_bf16(pa[s][0], vb0, acc[s][ds], 0, 0, 0);
        acc[s][ds] = __builtin_amdgcn_mfma_f32_16x16x32_bf16(pa[s][1], vb1, acc[s][ds], 0, 0, 0);
      }
    }
  }
  // denominators: reduce over quad groups (2 shuffles), stash in LDS for the divide
#pragma unroll
  for (int s = 0; s < 2; s++) {
    float d = dpart[s];
    d += __shfl_xor(d, 16);
    d += __shfl_xor(d, 32);
    if (quad == 0) Dn[wave*64 + s*16 + ln] = d;
  }
  // write ctx [T,B,D] bf16 (DS ops in-order per wave: Dn visible without barrier)
#pragma unroll
  for (int s = 0; s < 2; s++) {
    int qrow = q0 + wave*32 + s*16 + quad*4;
#pragma unroll
    for (int r = 0; r < 4; r++) {
      float invd = 1.f / Dn[wave*64 + s*16 + quad*4 + r];
      size_t o = ((size_t)t*B_ + (qrow + r))*D_ + h*HD_ + ln;
#pragma unroll
      for (int ds = 0; ds < 4; ds++)
        ctx[o + ds*16] = f2b(acc[s][ds][r] * invd);
    }
  }
}

// ---- Norms + partial mean-normalized vectors (bf16 input). 512 blocks. ----
__global__ __launch_bounds__(256) void k_norms1(const unsigned short* __restrict__ outb,
                                                float* __restrict__ norms,
                                                float* __restrict__ pmvec)
{
  __shared__ float wsum[4*768];
  int blk = blockIdx.x;            // t*8 + c
  int t = blk >> 3, c = blk & 7;
  int wave = threadIdx.x >> 6, lane = threadIdx.x & 63;
  float macc[12];
#pragma unroll
  for (int j = 0; j < 12; j++) macc[j] = 0.f;
  for (int i = 0; i < 16; i++) {
    int b = c*64 + wave*16 + i;
    const unsigned short* row = &outb[((size_t)t*B_ + b)*D_];
    float x[12]; float ss = 0.f;
#pragma unroll
    for (int j = 0; j < 12; j++) { x[j] = b2f(row[lane + 64*j]); ss += x[j]*x[j]; }
#pragma unroll
    for (int off = 32; off; off >>= 1) ss += __shfl_xor(ss, off);
    float nr = fmaxf(sqrtf(ss), 1e-8f);
    if (lane == 0) norms[(size_t)t*B_ + b] = nr;
    float inv = 1.f / nr;
#pragma unroll
    for (int j = 0; j < 12; j++) macc[j] += x[j]*inv;
  }
#pragma unroll
  for (int j = 0; j < 12; j++) wsum[wave*768 + 64*j + lane] = macc[j];
  __syncthreads();
  for (int d = threadIdx.x; d < 768; d += 256) {
    pmvec[(size_t)blk*768 + d] = wsum[d] + wsum[768 + d] + wsum[1536 + d] + wsum[2304 + d];
  }
}

// ---- reduce 8 partials -> mvec[t] ----
__global__ __launch_bounds__(256) void k_norms2(const float* __restrict__ pmvec,
                                                float* __restrict__ mvec)
{
  int t = blockIdx.x;
  for (int d = threadIdx.x; d < 768; d += 256) {
    float s = 0.f;
#pragma unroll
    for (int c = 0; c < 8; c++) s += pmvec[(size_t)(t*8 + c)*768 + d];
    mvec[t*768 + d] = s * (1.0f/512.0f);
  }
}

// ---- adj[t,b] = mvec[t] . out[t,b] / norms[t,b]. One wave per row (bf16 input). ----
__global__ __launch_bounds__(256) void k_adj(const unsigned short* __restrict__ outb,
                                             const float* __restrict__ norms,
                                             const float* __restrict__ mvec,
                                             float* __restrict__ adj)
{
  int idx = blockIdx.x*4 + (threadIdx.x >> 6);   // 0..32767
  int lane = threadIdx.x & 63;
  int t = idx >> 9;
  const unsigned short* row = &outb[(size_t)idx*768];
  const float* m = &mvec[t*768];
  float dot = 0.f;
#pragma unroll
  for (int j = 0; j < 12; j++) dot += b2f(row[lane + 64*j]) * m[lane + 64*j];
#pragma unroll
  for (int off = 32; off; off >>= 1) dot += __shfl_xor(dot, off);
  if (lane == 0) adj[idx] = dot / norms[idx];
}

extern "C" void kernel_launch(void* const* d_in, const int* in_sizes, int n_in,
                              void* d_out, int out_size, void* d_ws, size_t ws_size,
                              hipStream_t stream)
{
  const float* node = (const float*)d_in[0];  // (64,512,768)
  const float* wqkv = (const float*)d_in[1];  // (2304,768)
  const float* bqkv = (const float*)d_in[2];  // (2304,)
  const float* wout = (const float*)d_in[3];  // (768,768)
  const float* bout = (const float*)d_in[4];  // (768,)
  float* adj = (float*)d_out;                 // (64,512,1)

  char* ws = (char*)d_ws;
  const size_t SZ = (size_t)M1*D_*2;          // 50,331,648 B (one bf16 [32768,768] buf)
  // Layout (~245 MiB). out_bf (48 MiB) aliases q (dead after attn).
  // pmvec (1.5 MiB) aliases x_bf (dead after qkv gemm).
  unsigned short* q_bf    = (unsigned short*)(ws);
  unsigned short* k_bf    = (unsigned short*)(ws + SZ);
  unsigned short* vT_bf   = (unsigned short*)(ws + 2*SZ);
  unsigned short* ctx_bf  = (unsigned short*)(ws + 3*SZ);
  unsigned short* x_bf    = (unsigned short*)(ws + 4*SZ);
  unsigned short* wqkv_bf = (unsigned short*)(ws + 5*SZ);
  unsigned short* wout_bf = (unsigned short*)(ws + 5*SZ + 3538944);
  unsigned short* out_bf  = (unsigned short*)(ws);                          // alias q
  float* pmvec            = (float*)(ws + 4*SZ);                            // alias x_bf
  float* norms            = (float*)(ws + 5*SZ + 3538944 + 1179648);
  float* mvec             = (float*)(ws + 5*SZ + 3538944 + 1179648 + 131072);

  // 1) fused casts to bf16
  k_cast_all<<<26880, 256, 0, stream>>>(node, wqkv, wout, x_bf, wqkv_bf, wout_bf);
  // 2) QKV projection (XCD-swizzled, LDS-repack coalesced epilogues)
  k_gemm_qkv<<<4608, 256, 0, stream>>>(x_bf, wqkv_bf, bqkv, q_bf, k_bf, vT_bf);
  // 3) attention (512 threads, 2 blocks/th: halved K/V staging redundancy)
  k_attn<<<1536, 512, 0, stream>>>(q_bf, k_bf, vT_bf, ctx_bf);
  // 4) out projection (LDS-repack epilogue) -> bf16 out (aliases q space)
  k_gemm_out<<<1536, 256, 0, stream>>>(ctx_bf, wout_bf, bout, out_bf);
  // 5) norms + mean normalized vector per t (512-block partial + reduce)
  k_norms1<<<T_*8, 256, 0, stream>>>(out_bf, norms, pmvec);
  k_norms2<<<T_, 256, 0, stream>>>(pmvec, mvec);
  // 6) adj = mvec . xn
  k_adj<<<M1/4, 256, 0, stream>>>(out_bf, norms, mvec, adj);
}